// Round 12
// baseline (1340.782 us; speedup 1.0000x reference)
//
#include <hip/hip_runtime.h>

#define S_TOT   10548
#define M_ROWS  21096
#define M_PAD   21120          // 330*64 = 660*32
#define E_DIM   256
#define NH_DIM  8
#define HD_DIM  32
#define DF_DIM  1024
#define NLAYERS 6

typedef unsigned short ushort_t;
typedef __attribute__((ext_vector_type(8))) short bf16x8;
typedef __attribute__((ext_vector_type(4))) float f32x4;

__device__ inline ushort_t f2bf(float f) {
    unsigned u = __float_as_uint(f);
    u += 0x7FFF + ((u >> 16) & 1);          // RNE
    return (ushort_t)(u >> 16);
}
__device__ inline float bf2f(ushort_t h) {
    return __uint_as_float(((unsigned)h) << 16);
}
__device__ inline f32x4 up2(unsigned a, unsigned b) {
    f32x4 v;
    v.x = __uint_as_float(a << 16);
    v.y = __uint_as_float(a & 0xffff0000u);
    v.z = __uint_as_float(b << 16);
    v.w = __uint_as_float(b & 0xffff0000u);
    return v;
}
// async global->LDS, 16B per lane; LDS dest wave-uniform, lane scatters at
// dest + lane*16.
__device__ inline void gload16(const ushort_t* g, ushort_t* l) {
    __builtin_amdgcn_global_load_lds(
        (const __attribute__((address_space(1))) void*)g,
        (__attribute__((address_space(3))) void*)l, 16, 0, 0);
}

// ---------------------------------------------------------------------------
// Input assembly: x fp32, posb bf16, xb = bf16(x), qb = bf16(x+pos)
// ---------------------------------------------------------------------------
__global__ __launch_bounds__(256)
void assemble_kernel(const float* __restrict__ f0, const float* __restrict__ p0,
                     const float* __restrict__ f1, const float* __restrict__ p1,
                     const float* __restrict__ f2, const float* __restrict__ p2,
                     const float* __restrict__ f3, const float* __restrict__ p3,
                     const float* __restrict__ lemb,
                     float* __restrict__ x, ushort_t* __restrict__ posb,
                     ushort_t* __restrict__ xb, ushort_t* __restrict__ qb)
{
    int idx = blockIdx.x * 256 + threadIdx.x;   // over M_ROWS*E
    int e = idx & (E_DIM - 1);
    int r = idx >> 8;
    int b = (r >= S_TOT) ? 1 : 0;
    int s = r - b * S_TOT;
    const float* f; const float* p; int lvl, j, n;
    if (s < 9216)       { lvl = 0; j = s;         n = 9216; f = f0; p = p0; }
    else if (s < 10368) { lvl = 1; j = s - 9216;  n = 1152; f = f1; p = p1; }
    else if (s < 10512) { lvl = 2; j = s - 10368; n = 144;  f = f2; p = p2; }
    else                { lvl = 3; j = s - 10512; n = 36;   f = f3; p = p3; }
    size_t o = (size_t)(b * E_DIM + e) * n + j;
    float xv = f[o];
    float pv = p[o] + lemb[lvl * E_DIM + e];
    x[idx]    = xv;
    posb[idx] = f2bf(pv);
    xb[idx]   = f2bf(xv);
    qb[idx]   = f2bf(xv + pv);
}

// ---------------------------------------------------------------------------
// Weight convert+transpose: src f32 [L,K,N] -> dst bf16 [L(stride), rowOff+N, K]
// ---------------------------------------------------------------------------
__global__ __launch_bounds__(256)
void transpose_cvt_kernel(const float* __restrict__ src, ushort_t* __restrict__ dst,
                          int K, int N, int dstLayerStride, int dstRowOff)
{
    __shared__ float tile[32][33];
    int l  = blockIdx.z;
    int n0 = blockIdx.x * 32, k0 = blockIdx.y * 32;
    int tx = threadIdx.x & 31, ty = threadIdx.x >> 5;
    const float* s = src + (size_t)l * K * N;
    ushort_t* d    = dst + (size_t)l * dstLayerStride + (size_t)dstRowOff * K;
    #pragma unroll
    for (int i = 0; i < 32; i += 8)
        tile[ty + i][tx] = s[(size_t)(k0 + ty + i) * N + n0 + tx];
    __syncthreads();
    #pragma unroll
    for (int i = 0; i < 32; i += 8)
        d[(size_t)(n0 + ty + i) * K + k0 + tx] = f2bf(tile[tx][ty + i]);
}

// ---------------------------------------------------------------------------
// 64x256-tile bf16 MFMA GEMM (part1), global_load_lds + XOR-swizzled LDS.
// grid.x=sup: 0=value (A=xb, permute store), 1=off[0:256),
// 2=off[256:384)+attn (A=qb); off/attn stored HEAD-MAJOR.
// ---------------------------------------------------------------------------
__global__ __launch_bounds__(256)
void gemm_part1(const ushort_t* __restrict__ A0, const ushort_t* __restrict__ A1,
                const ushort_t* __restrict__ BtBase,
                const float* __restrict__ b1, const float* __restrict__ b2,
                const float* __restrict__ b3,
                ushort_t* __restrict__ O1, ushort_t* __restrict__ O2,
                ushort_t* __restrict__ O3, int M)
{
    __shared__ short As[64 * 32];
    __shared__ short Bs[256 * 32];
    const int K = 256;
    int t    = threadIdx.x;
    int sup  = blockIdx.x;
    int row0 = blockIdx.y * 64;
    int lane = t & 63;
    int w    = t >> 6;
    int wn   = w * 64;
    const int quad = lane >> 4, lrow = lane & 15;

    const ushort_t* A  = (sup != 0) ? A1 : A0;
    const ushort_t* Bt = BtBase + (size_t)sup * 256 * K;

    f32x4 acc[4][4];
    #pragma unroll
    for (int i = 0; i < 4; ++i)
        #pragma unroll
        for (int j = 0; j < 4; ++j)
            acc[i][j] = (f32x4){0.f, 0.f, 0.f, 0.f};

    int srow = lane >> 2;
    const int sw = (((lane & 3) ^ ((lane >> 3) & 3)) * 8);     // swizzled k-seg
    const int rs = ((quad ^ ((lrow >> 1) & 3)) * 8);           // fragment slot
    const ushort_t* Ag = A + (size_t)(row0 + w * 16 + srow) * K + sw;
    const ushort_t* Bg = Bt + (size_t)(w * 64 + srow) * K + sw;
    ushort_t* Al = (ushort_t*)&As[(w * 16) * 32];

    for (int k0 = 0; k0 < K; k0 += 32) {
        gload16(Ag + k0, Al);
        #pragma unroll
        for (int q = 0; q < 4; ++q)
            gload16(Bg + (size_t)(q * 16) * K + k0,
                    (ushort_t*)&Bs[(w * 64 + q * 16) * 32]);
        __syncthreads();
        bf16x8 af[4], bfr[4];
        #pragma unroll
        for (int i = 0; i < 4; ++i)
            af[i] = *(const bf16x8*)&As[(i * 16 + lrow) * 32 + rs];
        #pragma unroll
        for (int j = 0; j < 4; ++j)
            bfr[j] = *(const bf16x8*)&Bs[(wn + j * 16 + lrow) * 32 + rs];
        #pragma unroll
        for (int i = 0; i < 4; ++i)
            #pragma unroll
            for (int j = 0; j < 4; ++j)
                acc[i][j] = __builtin_amdgcn_mfma_f32_16x16x32_bf16(af[i], bfr[j], acc[i][j], 0, 0, 0);
        __syncthreads();
    }

    #pragma unroll
    for (int j = 0; j < 4; ++j) {
        int col = wn + j * 16 + lrow;     // 0..255 local
        float bia = (sup == 0) ? b1[col]
                  : (sup == 1) ? b2[col]
                  : (col < 128) ? b2[256 + col] : b3[col - 128];
        #pragma unroll
        for (int i = 0; i < 4; ++i)
            #pragma unroll
            for (int rg = 0; rg < 4; ++rg) {
                int row = row0 + i * 16 + quad * 4 + rg;
                if (row < M) {
                    float v = acc[i][j][rg] + bia;
                    if (sup == 0) {
                        int b = (row >= S_TOT) ? 1 : 0;
                        int s = row - b * S_TOT;
                        O1[(((size_t)(b * NH_DIM + (col >> 5))) * S_TOT + s) * HD_DIM + (col & 31)] = f2bf(v);
                    } else if (sup == 2 && col >= 128) {
                        int acol = col - 128;
                        O3[((size_t)(acol >> 4) * M_ROWS + row) * 16 + (acol & 15)] = f2bf(v);
                    } else {
                        int ocol = (sup == 1) ? col : 256 + col;
                        int hh = (ocol * 1366) >> 16;            // /48
                        O2[((size_t)hh * M_ROWS + row) * 48 + (ocol - hh * 48)] = f2bf(v);
                    }
                }
            }
    }
}

// ---------------------------------------------------------------------------
// FUSED TAIL: out-proj + residual + LN1 + FFN + residual + LN2.
// 32-row block. A(sampb) resident in LDS (swizzled, key=row&7); LN1 output
// kept fp32 in registers (LN2 residual) and re-deposited bf16 into the same
// LDS region as ff1's A. Hidden chunk lives in LDS. Writes x, xb, qb.
// ---------------------------------------------------------------------------
__global__ __launch_bounds__(256)
void tail_kernel(const ushort_t* __restrict__ sampA, const ushort_t* __restrict__ Wp,
                 const float* __restrict__ b_out,
                 const float* __restrict__ ln1g, const float* __restrict__ ln1b,
                 const ushort_t* __restrict__ W1t, const ushort_t* __restrict__ W2t,
                 const float* __restrict__ bias1, const float* __restrict__ bias2,
                 const float* __restrict__ ln2g, const float* __restrict__ ln2b,
                 float* __restrict__ x, ushort_t* __restrict__ xb,
                 ushort_t* __restrict__ qb, const ushort_t* __restrict__ posb,
                 int M)
{
    __shared__ short AsF[32 * 256];   // A rows (full K), slot = kseg ^ (row&7)
    __shared__ short Bs[256 * 32];    // per-iter B tile, swizzled
    __shared__ short Hs[32 * 264];    // hidden chunk (padded stride)
    __shared__ float red1[32 * 5], red2[32 * 5];

    int t    = threadIdx.x;
    int row0 = blockIdx.x * 32;
    int lane = t & 63;
    int w    = t >> 6;
    int wn   = w * 64;
    const int quad = lane >> 4, lrow = lane & 15;
    int srow = lane >> 2;
    const int sw = (((lane & 3) ^ ((lane >> 3) & 3)) * 8);
    const int rs = ((quad ^ ((lrow >> 1) & 3)) * 8);
    const int rkey = lrow & 7;        // for AsF fragment reads (row&7)

    // ---- stage A (sampb rows) into AsF, swizzled ----
    #pragma unroll
    for (int R = 0; R < 4; ++R) {
        int rl   = R * 8 + w * 2 + (lane >> 5);
        int slot = lane & 31;
        int kseg = slot ^ (rl & 7);
        gload16(sampA + (size_t)(row0 + rl) * 256 + kseg * 8,
                (ushort_t*)&AsF[(R * 8 + w * 2) * 256]);
    }

    // ---- GEMM_out: acc1 = sampA @ Wp^T ----
    f32x4 acc1[2][4];
    #pragma unroll
    for (int i = 0; i < 2; ++i)
        #pragma unroll
        for (int j = 0; j < 4; ++j)
            acc1[i][j] = (f32x4){0.f, 0.f, 0.f, 0.f};
    {
        const ushort_t* Bg = Wp + (size_t)(w * 64 + srow) * 256 + sw;
        for (int kk = 0; kk < 8; ++kk) {
            #pragma unroll
            for (int q = 0; q < 4; ++q)
                gload16(Bg + (size_t)(q * 16) * 256 + kk * 32,
                        (ushort_t*)&Bs[(w * 64 + q * 16) * 32]);
            __syncthreads();
            bf16x8 af[2], bfr[4];
            #pragma unroll
            for (int i = 0; i < 2; ++i)
                af[i] = *(const bf16x8*)&AsF[(i * 16 + lrow) * 256 + (((kk * 4 + quad) ^ rkey) * 8)];
            #pragma unroll
            for (int j = 0; j < 4; ++j)
                bfr[j] = *(const bf16x8*)&Bs[(wn + j * 16 + lrow) * 32 + rs];
            #pragma unroll
            for (int i = 0; i < 2; ++i)
                #pragma unroll
                for (int j = 0; j < 4; ++j)
                    acc1[i][j] = __builtin_amdgcn_mfma_f32_16x16x32_bf16(af[i], bfr[j], acc1[i][j], 0, 0, 0);
            __syncthreads();
        }
    }

    // ---- epilogue 1: v1 = LN1(x + out-proj + b_out); keep v1 in regs, xb1->AsF
    float g1[4], be1[4], bo[4];
    #pragma unroll
    for (int j = 0; j < 4; ++j) {
        int col = wn + j * 16 + lrow;
        g1[j] = ln1g[col]; be1[j] = ln1b[col]; bo[j] = b_out[col];
    }
    #pragma unroll
    for (int i = 0; i < 2; ++i)
        #pragma unroll
        for (int rg = 0; rg < 4; ++rg) {
            int row = row0 + i * 16 + quad * 4 + rg;
            #pragma unroll
            for (int j = 0; j < 4; ++j) {
                int col = wn + j * 16 + lrow;
                float xres = (row < M) ? x[(size_t)row * 256 + col] : 0.f;
                acc1[i][j][rg] += bo[j] + xres;
            }
            float p1 = acc1[i][0][rg] + acc1[i][1][rg] + acc1[i][2][rg] + acc1[i][3][rg];
            float p2 = acc1[i][0][rg] * acc1[i][0][rg] + acc1[i][1][rg] * acc1[i][1][rg]
                     + acc1[i][2][rg] * acc1[i][2][rg] + acc1[i][3][rg] * acc1[i][3][rg];
            p1 += __shfl_xor(p1, 1); p2 += __shfl_xor(p2, 1);
            p1 += __shfl_xor(p1, 2); p2 += __shfl_xor(p2, 2);
            p1 += __shfl_xor(p1, 4); p2 += __shfl_xor(p2, 4);
            p1 += __shfl_xor(p1, 8); p2 += __shfl_xor(p2, 8);
            if (lrow == 0) {
                int rl = i * 16 + quad * 4 + rg;
                red1[rl * 5 + w] = p1;
                red2[rl * 5 + w] = p2;
            }
        }
    __syncthreads();
    #pragma unroll
    for (int i = 0; i < 2; ++i)
        #pragma unroll
        for (int rg = 0; rg < 4; ++rg) {
            int rl = i * 16 + quad * 4 + rg;
            float S1 = red1[rl * 5 + 0] + red1[rl * 5 + 1] + red1[rl * 5 + 2] + red1[rl * 5 + 3];
            float S2 = red2[rl * 5 + 0] + red2[rl * 5 + 1] + red2[rl * 5 + 2] + red2[rl * 5 + 3];
            float mean = S1 * (1.f / 256);
            float rstd = rsqrtf(S2 * (1.f / 256) - mean * mean + 1e-5f);
            #pragma unroll
            for (int j = 0; j < 4; ++j) {
                int col = wn + j * 16 + lrow;
                float v = (acc1[i][j][rg] - mean) * rstd * g1[j] + be1[j];
                acc1[i][j][rg] = v;   // fp32 LN1 output = LN2 residual
                AsF[rl * 256 + (((col >> 3) ^ (rl & 7)) * 8) + (col & 7)] = f2bf(v);
            }
        }

    // ---- FFN: acc2 = relu(v1b @ W1^T + b1) @ W2^T ----
    f32x4 acc2[2][4];
    #pragma unroll
    for (int i = 0; i < 2; ++i)
        #pragma unroll
        for (int j = 0; j < 4; ++j)
            acc2[i][j] = (f32x4){0.f, 0.f, 0.f, 0.f};

    for (int c = 0; c < 4; ++c) {
        f32x4 hh[2][4];
        #pragma unroll
        for (int i = 0; i < 2; ++i)
            #pragma unroll
            for (int j = 0; j < 4; ++j)
                hh[i][j] = (f32x4){0.f, 0.f, 0.f, 0.f};

        const ushort_t* B1g = W1t + (size_t)(c * 256 + w * 64 + srow) * 256 + sw;
        for (int kk = 0; kk < 8; ++kk) {
            #pragma unroll
            for (int q = 0; q < 4; ++q)
                gload16(B1g + (size_t)(q * 16) * 256 + kk * 32,
                        (ushort_t*)&Bs[(w * 64 + q * 16) * 32]);
            __syncthreads();
            bf16x8 af[2], bfr[4];
            #pragma unroll
            for (int i = 0; i < 2; ++i)
                af[i] = *(const bf16x8*)&AsF[(i * 16 + lrow) * 256 + (((kk * 4 + quad) ^ rkey) * 8)];
            #pragma unroll
            for (int j = 0; j < 4; ++j)
                bfr[j] = *(const bf16x8*)&Bs[(wn + j * 16 + lrow) * 32 + rs];
            #pragma unroll
            for (int i = 0; i < 2; ++i)
                #pragma unroll
                for (int j = 0; j < 4; ++j)
                    hh[i][j] = __builtin_amdgcn_mfma_f32_16x16x32_bf16(af[i], bfr[j], hh[i][j], 0, 0, 0);
            __syncthreads();
        }
        // hidden chunk -> Hs (bias + relu)
        #pragma unroll
        for (int j = 0; j < 4; ++j) {
            int col = wn + j * 16 + lrow;
            float b1v = bias1[c * 256 + col];
            #pragma unroll
            for (int i = 0; i < 2; ++i)
                #pragma unroll
                for (int rg = 0; rg < 4; ++rg) {
                    int rl = i * 16 + quad * 4 + rg;
                    Hs[rl * 264 + col] = f2bf(fmaxf(hh[i][j][rg] + b1v, 0.f));
                }
        }
        const ushort_t* B2g = W2t + (size_t)(w * 64 + srow) * 1024 + c * 256 + sw;
        for (int kk = 0; kk < 8; ++kk) {
            #pragma unroll
            for (int q = 0; q < 4; ++q)
                gload16(B2g + (size_t)(q * 16) * 1024 + kk * 32,
                        (ushort_t*)&Bs[(w * 64 + q * 16) * 32]);
            __syncthreads();
            bf16x8 af[2], bfr[4];
            #pragma unroll
            for (int i = 0; i < 2; ++i)
                af[i] = *(const bf16x8*)&Hs[(i * 16 + lrow) * 264 + kk * 32 + quad * 8];
            #pragma unroll
            for (int j = 0; j < 4; ++j)
                bfr[j] = *(const bf16x8*)&Bs[(wn + j * 16 + lrow) * 32 + rs];
            #pragma unroll
            for (int i = 0; i < 2; ++i)
                #pragma unroll
                for (int j = 0; j < 4; ++j)
                    acc2[i][j] = __builtin_amdgcn_mfma_f32_16x16x32_bf16(af[i], bfr[j], acc2[i][j], 0, 0, 0);
            __syncthreads();
        }
    }

    // ---- epilogue 2: x = LN2(v1 + ffn + b2); write x, xb, qb ----
    float g2[4], be2[4], b2v[4];
    #pragma unroll
    for (int j = 0; j < 4; ++j) {
        int col = wn + j * 16 + lrow;
        g2[j] = ln2g[col]; be2[j] = ln2b[col]; b2v[j] = bias2[col];
    }
    #pragma unroll
    for (int i = 0; i < 2; ++i)
        #pragma unroll
        for (int rg = 0; rg < 4; ++rg) {
            #pragma unroll
            for (int j = 0; j < 4; ++j)
                acc2[i][j][rg] += b2v[j] + acc1[i][j][rg];
            float p1 = acc2[i][0][rg] + acc2[i][1][rg] + acc2[i][2][rg] + acc2[i][3][rg];
            float p2 = acc2[i][0][rg] * acc2[i][0][rg] + acc2[i][1][rg] * acc2[i][1][rg]
                     + acc2[i][2][rg] * acc2[i][2][rg] + acc2[i][3][rg] * acc2[i][3][rg];
            p1 += __shfl_xor(p1, 1); p2 += __shfl_xor(p2, 1);
            p1 += __shfl_xor(p1, 2); p2 += __shfl_xor(p2, 2);
            p1 += __shfl_xor(p1, 4); p2 += __shfl_xor(p2, 4);
            p1 += __shfl_xor(p1, 8); p2 += __shfl_xor(p2, 8);
            if (lrow == 0) {
                int rl = i * 16 + quad * 4 + rg;
                red1[rl * 5 + w] = p1;
                red2[rl * 5 + w] = p2;
            }
        }
    __syncthreads();
    #pragma unroll
    for (int i = 0; i < 2; ++i)
        #pragma unroll
        for (int rg = 0; rg < 4; ++rg) {
            int rl = i * 16 + quad * 4 + rg;
            float S1 = red1[rl * 5 + 0] + red1[rl * 5 + 1] + red1[rl * 5 + 2] + red1[rl * 5 + 3];
            float S2 = red2[rl * 5 + 0] + red2[rl * 5 + 1] + red2[rl * 5 + 2] + red2[rl * 5 + 3];
            float mean = S1 * (1.f / 256);
            float rstd = rsqrtf(S2 * (1.f / 256) - mean * mean + 1e-5f);
            int row = row0 + rl;
            if (row < M) {
                #pragma unroll
                for (int j = 0; j < 4; ++j) {
                    int col = wn + j * 16 + lrow;
                    float out = (acc2[i][j][rg] - mean) * rstd * g2[j] + be2[j];
                    size_t o = (size_t)row * 256 + col;
                    x[o]  = out;
                    xb[o] = f2bf(out);
                    qb[o] = f2bf(out + bf2f(posb[o]));
                }
            }
        }
}

// ---------------------------------------------------------------------------
// Fused deformable sampling, v7: XCD-pinned heads + 16B-lane gathers +
// relaxed VGPR cap for deep load pipelining.
// ---------------------------------------------------------------------------
__global__ __launch_bounds__(256, 4)
void sample_kernel(const ushort_t* __restrict__ valueb,
                   const ushort_t* __restrict__ offh,   // [NH][M][48]
                   const ushort_t* __restrict__ attnh,  // [NH][M][16]
                   ushort_t* __restrict__ sampb)
{
    __shared__ float wrec[16 * 168];
    __shared__ int   idxA[16 * 40];

    const int LD_[4]  = {4, 2, 1, 1};
    const int LH_[4]  = {48, 24, 12, 6};
    const int LW_[4]  = {48, 24, 12, 6};
    const int LS0_[4] = {0, 9216, 10368, 10512};

    int t   = threadIdx.x;
    int gl  = t >> 4;                   // local group 0..15
    int sub = t & 15;
    int h   = blockIdx.x;
    int r   = blockIdx.y * 16 + gl;
    bool valid = (r < M_ROWS);
    if (!valid) r = M_ROWS - 1;
    int b   = (r >= S_TOT) ? 1 : 0;
    int s   = r - b * S_TOT;

    float rx, ry, rz;
    {
        int j;
        if (s < 9216)       { j = s;         int qx = j % 48; int q2 = j / 48; int qy = q2 % 48; int qz = q2 / 48;
                              rx = (qx + 0.5f) * (1.f/48); ry = (qy + 0.5f) * (1.f/48); rz = (qz + 0.5f) * (1.f/4); }
        else if (s < 10368) { j = s - 9216;  int qx = j % 24; int q2 = j / 24; int qy = q2 % 24; int qz = q2 / 24;
                              rx = (qx + 0.5f) * (1.f/24); ry = (qy + 0.5f) * (1.f/24); rz = (qz + 0.5f) * (1.f/2); }
        else if (s < 10512) { j = s - 10368; int qx = j % 12; int qy = j / 12;
                              rx = (qx + 0.5f) * (1.f/12); ry = (qy + 0.5f) * (1.f/12); rz = 0.5f; }
        else                { j = s - 10512; int qx = j % 6;  int qy = j / 6;
                              rx = (qx + 0.5f) * (1.f/6);  ry = (qy + 0.5f) * (1.f/6);  rz = 0.5f; }
    }

    // ---- phase 1: one point per lane ----
    {
        int p = sub;
        float lg = bf2f(attnh[((size_t)h * M_ROWS + r) * 16 + p]);
        float mx = lg;
        mx = fmaxf(mx, __shfl_xor(mx, 1));
        mx = fmaxf(mx, __shfl_xor(mx, 2));
        mx = fmaxf(mx, __shfl_xor(mx, 4));
        mx = fmaxf(mx, __shfl_xor(mx, 8));
        float e = __expf(lg - mx);
        float sm = e;
        sm += __shfl_xor(sm, 1);
        sm += __shfl_xor(sm, 2);
        sm += __shfl_xor(sm, 4);
        sm += __shfl_xor(sm, 8);
        float aw = e / sm;

        int lvl = p >> 2;
        const int Dl = LD_[lvl], Hl = LH_[lvl], Wl = LW_[lvl];
        size_t base3 = ((size_t)h * M_ROWS + r) * 48 + p * 3;
        float cx = rx * Wl + bf2f(offh[base3 + 0]) - 0.5f;
        float cy = ry * Hl + bf2f(offh[base3 + 1]) - 0.5f;
        float cz = rz * Dl + bf2f(offh[base3 + 2]) - 0.5f;
        float xf = floorf(cx), yf = floorf(cy), zf = floorf(cz);
        float fx = cx - xf, fy = cy - yf, fz = cz - zf;
        int x0 = (int)xf, y0 = (int)yf, z0 = (int)zf;
        float wx0 = ((unsigned)x0       < (unsigned)Wl) ? 1.f - fx : 0.f;
        float wx1 = ((unsigned)(x0 + 1) < (unsigned)Wl) ? fx       : 0.f;
        float wy0 = ((unsigned)y0       < (unsigned)Hl) ? 1.f - fy : 0.f;
        float wy1 = ((unsigned)(y0 + 1) < (unsigned)Hl) ? fy       : 0.f;
        float wz0 = ((unsigned)z0       < (unsigned)Dl) ? (1.f - fz) * aw : 0.f;
        float wz1 = ((unsigned)(z0 + 1) < (unsigned)Dl) ? fz * aw       : 0.f;
        int xc = min(max(x0, -1), Wl - 1);
        int yc = min(max(y0, -1), Hl - 1);
        int zc = min(max(z0, -1), Dl - 1);
        int idx = LS0_[lvl] + (zc * Hl + yc) * Wl + xc;

        float* wp = &wrec[gl * 168 + p * 8];
        *(f32x4*)wp       = (f32x4){wz0 * wy0 * wx0, wz0 * wy0 * wx1,
                                    wz0 * wy1 * wx0, wz0 * wy1 * wx1};
        *(f32x4*)(wp + 4) = (f32x4){wz1 * wy0 * wx0, wz1 * wy0 * wx1,
                                    wz1 * wy1 * wx0, wz1 * wy1 * wx1};
        idxA[gl * 40 + p] = idx;
    }
    __syncthreads();

    // ---- phase 2: corner cr = (dy,dx), channel octet q ----
    int q  = sub & 3;
    int cr = sub >> 2;
    int dy = cr >> 1, dx = cr & 1;
    const ushort_t* vb = valueb + ((size_t)(b * NH_DIM + h) * S_TOT) * HD_DIM + q * 8;
    f32x4 accA = (f32x4){0.f, 0.f, 0.f, 0.f};
    f32x4 accB = (f32x4){0.f, 0.f, 0.f, 0.f};

    #pragma unroll
    for (int p = 0; p < 16; ++p) {
        const int lvl = p >> 2;
        const int Wl = LW_[lvl];
        const int HW = LH_[lvl] * LW_[lvl];
        float w0 = wrec[gl * 168 + p * 8 + cr];
        float w1 = wrec[gl * 168 + p * 8 + 4 + cr];
        int idx = idxA[gl * 40 + p] + dy * Wl + dx;
        const ushort_t* cb = vb + (long long)idx * HD_DIM;
        uint4 u0 = *(const uint4*)cb;
        uint4 u1 = *(const uint4*)(cb + HW * HD_DIM);
        accA += w0 * up2(u0.x, u0.y);
        accB += w0 * up2(u0.z, u0.w);
        accA += w1 * up2(u1.x, u1.y);
        accB += w1 * up2(u1.z, u1.w);
    }

    accA.x += __shfl_xor(accA.x, 4); accA.y += __shfl_xor(accA.y, 4);
    accA.z += __shfl_xor(accA.z, 4); accA.w += __shfl_xor(accA.w, 4);
    accB.x += __shfl_xor(accB.x, 4); accB.y += __shfl_xor(accB.y, 4);
    accB.z += __shfl_xor(accB.z, 4); accB.w += __shfl_xor(accB.w, 4);
    accA.x += __shfl_xor(accA.x, 8); accA.y += __shfl_xor(accA.y, 8);
    accA.z += __shfl_xor(accA.z, 8); accA.w += __shfl_xor(accA.w, 8);
    accB.x += __shfl_xor(accB.x, 8); accB.y += __shfl_xor(accB.y, 8);
    accB.z += __shfl_xor(accB.z, 8); accB.w += __shfl_xor(accB.w, 8);

    if (cr == 0 && valid) {
        ushort4 o1, o2;
        o1.x = f2bf(accA.x); o1.y = f2bf(accA.y); o1.z = f2bf(accA.z); o1.w = f2bf(accA.w);
        o2.x = f2bf(accB.x); o2.y = f2bf(accB.y); o2.z = f2bf(accB.z); o2.w = f2bf(accB.w);
        ushort_t* op = sampb + (size_t)r * E_DIM + h * HD_DIM + q * 8;
        *(ushort4*)op       = o1;
        *(ushort4*)(op + 4) = o2;
    }
}

// ---------------------------------------------------------------------------
extern "C" void kernel_launch(void* const* d_in, const int* in_sizes, int n_in,
                              void* d_out, int out_size, void* d_ws, size_t ws_size,
                              hipStream_t stream)
{
    const float* f0     = (const float*)d_in[0];
    const float* p0     = (const float*)d_in[1];
    const float* f1     = (const float*)d_in[2];
    const float* p1     = (const float*)d_in[3];
    const float* f2     = (const float*)d_in[4];
    const float* p2     = (const float*)d_in[5];
    const float* f3     = (const float*)d_in[6];
    const float* p3     = (const float*)d_in[7];
    const float* lemb   = (const float*)d_in[8];
    const float* W_off  = (const float*)d_in[9];
    const float* b_off  = (const float*)d_in[10];
    const float* W_attn = (const float*)d_in[11];
    const float* b_attn = (const float*)d_in[12];
    const float* W_val  = (const float*)d_in[13];
    const float* b_val  = (const float*)d_in[14];
    const float* W_out  = (const float*)d_in[15];
    const float* b_out  = (const float*)d_in[16];
    const float* ln1_g  = (const float*)d_in[17];
    const float* ln1_b  = (const float*)d_in[18];
    const float* W_ff1  = (const float*)d_in[19];
    const float* b_ff1  = (const float*)d_in[20];
    const float* W_ff2  = (const float*)d_in[21];
    const float* b_ff2  = (const float*)d_in[22];
    const float* ln2_g  = (const float*)d_in[23];
    const float* ln2_b  = (const float*)d_in[24];

    float* x = (float*)d_out;
    char*  w = (char*)d_ws;

    // ws layout (bytes)
    ushort_t* posb   = (ushort_t*)(w + 0);                   // 10,813,440
    // value region: 256KB front guard | (B,NH,S,HD) bf16 | 128KB back guard
    ushort_t* valueb = (ushort_t*)(w + 21626880 + 262144);
    char*     region =            (w + 34525184);            // 43,253,760
    ushort_t* offh   = (ushort_t*)(region);                  // [NH][M][48] 16,220,160
    ushort_t* attnh  = (ushort_t*)(region + 16220160);       // [NH][M][16]  5,406,720
    ushort_t* sampb  = (ushort_t*)(region + 21626880);       // 10,813,440 (+tail slack)
    ushort_t* xb     = (ushort_t*)(w + 77778944);            // 10,813,440
    ushort_t* qb     = (ushort_t*)(w + 88592384);            // 10,813,440
    ushort_t* wb     = (ushort_t*)(w + 99405824);            //  9,437,184

    // Combined attention weight: per layer 768 rows x 256 K
    ushort_t* Wc_t = wb;              // [6][768][256]
    ushort_t* Wp_t = wb + 1179648;    // [6][256][256]
    ushort_t* W1_t = wb + 1572864;    // [6][1024][256]
    ushort_t* W2_t = wb + 3145728;    // [6][256][1024]

    dim3 blk(256);

    transpose_cvt_kernel<<<dim3(8, 8, 6),  blk, 0, stream>>>(W_val,  Wc_t, 256, 256,  196608, 0);
    transpose_cvt_kernel<<<dim3(12, 8, 6), blk, 0, stream>>>(W_off,  Wc_t, 256, 384,  196608, 256);
    transpose_cvt_kernel<<<dim3(4, 8, 6),  blk, 0, stream>>>(W_attn, Wc_t, 256, 128,  196608, 640);
    transpose_cvt_kernel<<<dim3(8, 8, 6),  blk, 0, stream>>>(W_out,  Wp_t, 256, 256,   65536, 0);
    transpose_cvt_kernel<<<dim3(32, 8, 6), blk, 0, stream>>>(W_ff1,  W1_t, 256, 1024, 262144, 0);
    transpose_cvt_kernel<<<dim3(8, 32, 6), blk, 0, stream>>>(W_ff2,  W2_t, 1024, 256, 262144, 0);

    assemble_kernel<<<(M_ROWS * E_DIM) / 256, blk, 0, stream>>>(
        f0, p0, f1, p1, f2, p2, f3, p3, lemb, x, posb, xb, qb);

    const int MT = M_PAD / 64;               // 330
    const int LT = M_PAD / 32;               // 660
    const int SB = (M_ROWS + 15) / 16;       // 1319
    for (int l = 0; l < NLAYERS; ++l) {
        gemm_part1<<<dim3(3, MT), blk, 0, stream>>>(
            xb, qb, Wc_t + l * 196608,
            b_val + l * 256, b_off + l * 384, b_attn + l * 128,
            valueb, offh, attnh, M_ROWS);
        sample_kernel<<<dim3(NH_DIM, SB), blk, 0, stream>>>(valueb, offh, attnh, sampb);
        tail_kernel<<<LT, blk, 0, stream>>>(
            sampb, Wp_t + l * 65536, b_out + l * 256,
            ln1_g + l * 256, ln1_b + l * 256,
            W1_t + l * 262144, W2_t + l * 262144,
            b_ff1 + l * 1024, b_ff2 + l * 256,
            ln2_g + l * 256, ln2_b + l * 256,
            x, xb, qb, posb, M_ROWS);
    }
}

// Round 13
// 1182.596 us; speedup vs baseline: 1.1338x; 1.1338x over previous
//
#include <hip/hip_runtime.h>

#define S_TOT   10548
#define M_ROWS  21096
#define M_PAD   21120          // 330*64 = 660*32
#define E_DIM   256
#define NH_DIM  8
#define HD_DIM  32
#define DF_DIM  1024
#define NLAYERS 6

typedef unsigned short ushort_t;
typedef __attribute__((ext_vector_type(8))) short bf16x8;
typedef __attribute__((ext_vector_type(4))) float f32x4;

__device__ inline ushort_t f2bf(float f) {
    unsigned u = __float_as_uint(f);
    u += 0x7FFF + ((u >> 16) & 1);          // RNE
    return (ushort_t)(u >> 16);
}
__device__ inline float bf2f(ushort_t h) {
    return __uint_as_float(((unsigned)h) << 16);
}
__device__ inline f32x4 up2(unsigned a, unsigned b) {
    f32x4 v;
    v.x = __uint_as_float(a << 16);
    v.y = __uint_as_float(a & 0xffff0000u);
    v.z = __uint_as_float(b << 16);
    v.w = __uint_as_float(b & 0xffff0000u);
    return v;
}
// async global->LDS, 16B per lane; LDS dest wave-uniform, lane scatters at
// dest + lane*16.
__device__ inline void gload16(const ushort_t* g, ushort_t* l) {
    __builtin_amdgcn_global_load_lds(
        (const __attribute__((address_space(1))) void*)g,
        (__attribute__((address_space(3))) void*)l, 16, 0, 0);
}

// ---------------------------------------------------------------------------
// Input assembly: x fp32, posb bf16, xb = bf16(x), qb = bf16(x+pos)
// ---------------------------------------------------------------------------
__global__ __launch_bounds__(256)
void assemble_kernel(const float* __restrict__ f0, const float* __restrict__ p0,
                     const float* __restrict__ f1, const float* __restrict__ p1,
                     const float* __restrict__ f2, const float* __restrict__ p2,
                     const float* __restrict__ f3, const float* __restrict__ p3,
                     const float* __restrict__ lemb,
                     float* __restrict__ x, ushort_t* __restrict__ posb,
                     ushort_t* __restrict__ xb, ushort_t* __restrict__ qb)
{
    int idx = blockIdx.x * 256 + threadIdx.x;   // over M_ROWS*E
    int e = idx & (E_DIM - 1);
    int r = idx >> 8;
    int b = (r >= S_TOT) ? 1 : 0;
    int s = r - b * S_TOT;
    const float* f; const float* p; int lvl, j, n;
    if (s < 9216)       { lvl = 0; j = s;         n = 9216; f = f0; p = p0; }
    else if (s < 10368) { lvl = 1; j = s - 9216;  n = 1152; f = f1; p = p1; }
    else if (s < 10512) { lvl = 2; j = s - 10368; n = 144;  f = f2; p = p2; }
    else                { lvl = 3; j = s - 10512; n = 36;   f = f3; p = p3; }
    size_t o = (size_t)(b * E_DIM + e) * n + j;
    float xv = f[o];
    float pv = p[o] + lemb[lvl * E_DIM + e];
    x[idx]    = xv;
    posb[idx] = f2bf(pv);
    xb[idx]   = f2bf(xv);
    qb[idx]   = f2bf(xv + pv);
}

// ---------------------------------------------------------------------------
// Weight convert+transpose: src f32 [L,K,N] -> dst bf16 [L(stride), rowOff+N, K]
// ---------------------------------------------------------------------------
__global__ __launch_bounds__(256)
void transpose_cvt_kernel(const float* __restrict__ src, ushort_t* __restrict__ dst,
                          int K, int N, int dstLayerStride, int dstRowOff)
{
    __shared__ float tile[32][33];
    int l  = blockIdx.z;
    int n0 = blockIdx.x * 32, k0 = blockIdx.y * 32;
    int tx = threadIdx.x & 31, ty = threadIdx.x >> 5;
    const float* s = src + (size_t)l * K * N;
    ushort_t* d    = dst + (size_t)l * dstLayerStride + (size_t)dstRowOff * K;
    #pragma unroll
    for (int i = 0; i < 32; i += 8)
        tile[ty + i][tx] = s[(size_t)(k0 + ty + i) * N + n0 + tx];
    __syncthreads();
    #pragma unroll
    for (int i = 0; i < 32; i += 8)
        d[(size_t)(n0 + ty + i) * K + k0 + tx] = f2bf(tile[tx][ty + i]);
}

// ---------------------------------------------------------------------------
// 64x256-tile bf16 MFMA GEMM (part1), global_load_lds + XOR-swizzled LDS.
// grid.x=sup: 0=value (A=xb, permute store), 1=off[0:256),
// 2=off[256:384)+attn (A=qb); off/attn stored HEAD-MAJOR.
// ---------------------------------------------------------------------------
__global__ __launch_bounds__(256)
void gemm_part1(const ushort_t* __restrict__ A0, const ushort_t* __restrict__ A1,
                const ushort_t* __restrict__ BtBase,
                const float* __restrict__ b1, const float* __restrict__ b2,
                const float* __restrict__ b3,
                ushort_t* __restrict__ O1, ushort_t* __restrict__ O2,
                ushort_t* __restrict__ O3, int M)
{
    __shared__ short As[64 * 32];
    __shared__ short Bs[256 * 32];
    const int K = 256;
    int t    = threadIdx.x;
    int sup  = blockIdx.x;
    int row0 = blockIdx.y * 64;
    int lane = t & 63;
    int w    = t >> 6;
    int wn   = w * 64;
    const int quad = lane >> 4, lrow = lane & 15;

    const ushort_t* A  = (sup != 0) ? A1 : A0;
    const ushort_t* Bt = BtBase + (size_t)sup * 256 * K;

    f32x4 acc[4][4];
    #pragma unroll
    for (int i = 0; i < 4; ++i)
        #pragma unroll
        for (int j = 0; j < 4; ++j)
            acc[i][j] = (f32x4){0.f, 0.f, 0.f, 0.f};

    int srow = lane >> 2;
    const int sw = (((lane & 3) ^ ((lane >> 3) & 3)) * 8);     // swizzled k-seg
    const int rs = ((quad ^ ((lrow >> 1) & 3)) * 8);           // fragment slot
    const ushort_t* Ag = A + (size_t)(row0 + w * 16 + srow) * K + sw;
    const ushort_t* Bg = Bt + (size_t)(w * 64 + srow) * K + sw;
    ushort_t* Al = (ushort_t*)&As[(w * 16) * 32];

    for (int k0 = 0; k0 < K; k0 += 32) {
        gload16(Ag + k0, Al);
        #pragma unroll
        for (int q = 0; q < 4; ++q)
            gload16(Bg + (size_t)(q * 16) * K + k0,
                    (ushort_t*)&Bs[(w * 64 + q * 16) * 32]);
        __syncthreads();
        bf16x8 af[4], bfr[4];
        #pragma unroll
        for (int i = 0; i < 4; ++i)
            af[i] = *(const bf16x8*)&As[(i * 16 + lrow) * 32 + rs];
        #pragma unroll
        for (int j = 0; j < 4; ++j)
            bfr[j] = *(const bf16x8*)&Bs[(wn + j * 16 + lrow) * 32 + rs];
        #pragma unroll
        for (int i = 0; i < 4; ++i)
            #pragma unroll
            for (int j = 0; j < 4; ++j)
                acc[i][j] = __builtin_amdgcn_mfma_f32_16x16x32_bf16(af[i], bfr[j], acc[i][j], 0, 0, 0);
        __syncthreads();
    }

    #pragma unroll
    for (int j = 0; j < 4; ++j) {
        int col = wn + j * 16 + lrow;     // 0..255 local
        float bia = (sup == 0) ? b1[col]
                  : (sup == 1) ? b2[col]
                  : (col < 128) ? b2[256 + col] : b3[col - 128];
        #pragma unroll
        for (int i = 0; i < 4; ++i)
            #pragma unroll
            for (int rg = 0; rg < 4; ++rg) {
                int row = row0 + i * 16 + quad * 4 + rg;
                if (row < M) {
                    float v = acc[i][j][rg] + bia;
                    if (sup == 0) {
                        int b = (row >= S_TOT) ? 1 : 0;
                        int s = row - b * S_TOT;
                        O1[(((size_t)(b * NH_DIM + (col >> 5))) * S_TOT + s) * HD_DIM + (col & 31)] = f2bf(v);
                    } else if (sup == 2 && col >= 128) {
                        int acol = col - 128;
                        O3[((size_t)(acol >> 4) * M_ROWS + row) * 16 + (acol & 15)] = f2bf(v);
                    } else {
                        int ocol = (sup == 1) ? col : 256 + col;
                        int hh = (ocol * 1366) >> 16;            // /48
                        O2[((size_t)hh * M_ROWS + row) * 48 + (ocol - hh * 48)] = f2bf(v);
                    }
                }
            }
    }
}

// ---------------------------------------------------------------------------
// 32x256-tile bf16 MFMA GEMM + FUSED residual + LayerNorm epilogue (out-proj).
// Swizzled LDS.
// ---------------------------------------------------------------------------
__global__ __launch_bounds__(256)
void gemm_ln(const ushort_t* __restrict__ A, const ushort_t* __restrict__ Bt,
             const float* __restrict__ bias,
             float* __restrict__ x, ushort_t* __restrict__ xb,
             const float* __restrict__ lng, const float* __restrict__ lnb,
             int M)
{
    __shared__ short As[32 * 32];
    __shared__ short Bs[256 * 32];
    __shared__ float red1[32 * 5];
    __shared__ float red2[32 * 5];
    const int K = 256;
    int t    = threadIdx.x;
    int row0 = blockIdx.x * 32;
    int lane = t & 63;
    int w    = t >> 6;
    int wn   = w * 64;
    const int quad = lane >> 4, lrow = lane & 15;

    f32x4 acc[2][4];
    #pragma unroll
    for (int i = 0; i < 2; ++i)
        #pragma unroll
        for (int j = 0; j < 4; ++j)
            acc[i][j] = (f32x4){0.f, 0.f, 0.f, 0.f};

    int srow = lane >> 2;
    const int sw = (((lane & 3) ^ ((lane >> 3) & 3)) * 8);
    const int rs = ((quad ^ ((lrow >> 1) & 3)) * 8);
    const ushort_t* Ag = A + (size_t)(row0 + w * 16 + srow) * K + sw;   // w<2
    const ushort_t* Bg = Bt + (size_t)(w * 64 + srow) * K + sw;
    ushort_t* Al = (ushort_t*)&As[(w * 16) * 32];

    for (int k0 = 0; k0 < K; k0 += 32) {
        if (w < 2) gload16(Ag + k0, Al);
        #pragma unroll
        for (int q = 0; q < 4; ++q)
            gload16(Bg + (size_t)(q * 16) * K + k0,
                    (ushort_t*)&Bs[(w * 64 + q * 16) * 32]);
        __syncthreads();
        bf16x8 af[2], bfr[4];
        #pragma unroll
        for (int i = 0; i < 2; ++i)
            af[i] = *(const bf16x8*)&As[(i * 16 + lrow) * 32 + rs];
        #pragma unroll
        for (int j = 0; j < 4; ++j)
            bfr[j] = *(const bf16x8*)&Bs[(wn + j * 16 + lrow) * 32 + rs];
        #pragma unroll
        for (int i = 0; i < 2; ++i)
            #pragma unroll
            for (int j = 0; j < 4; ++j)
                acc[i][j] = __builtin_amdgcn_mfma_f32_16x16x32_bf16(af[i], bfr[j], acc[i][j], 0, 0, 0);
        __syncthreads();
    }

    // ---- fused epilogue: v = x + (y + bias); LayerNorm per row ----
    float gj[4], bj[4], bi[4];
    #pragma unroll
    for (int j = 0; j < 4; ++j) {
        int col = wn + j * 16 + lrow;
        gj[j] = lng[col];
        bj[j] = lnb[col];
        bi[j] = bias[col];
    }

    #pragma unroll
    for (int i = 0; i < 2; ++i)
        #pragma unroll
        for (int rg = 0; rg < 4; ++rg) {
            int row = row0 + i * 16 + quad * 4 + rg;
            #pragma unroll
            for (int j = 0; j < 4; ++j) {
                int col = wn + j * 16 + lrow;
                float xres = (row < M) ? x[(size_t)row * 256 + col] : 0.f;
                acc[i][j][rg] += bi[j] + xres;
            }
            float p1 = acc[i][0][rg] + acc[i][1][rg] + acc[i][2][rg] + acc[i][3][rg];
            float p2 = acc[i][0][rg] * acc[i][0][rg] + acc[i][1][rg] * acc[i][1][rg]
                     + acc[i][2][rg] * acc[i][2][rg] + acc[i][3][rg] * acc[i][3][rg];
            p1 += __shfl_xor(p1, 1); p2 += __shfl_xor(p2, 1);
            p1 += __shfl_xor(p1, 2); p2 += __shfl_xor(p2, 2);
            p1 += __shfl_xor(p1, 4); p2 += __shfl_xor(p2, 4);
            p1 += __shfl_xor(p1, 8); p2 += __shfl_xor(p2, 8);
            if (lrow == 0) {
                int rl = i * 16 + quad * 4 + rg;
                red1[rl * 5 + w] = p1;
                red2[rl * 5 + w] = p2;
            }
        }
    __syncthreads();

    #pragma unroll
    for (int i = 0; i < 2; ++i)
        #pragma unroll
        for (int rg = 0; rg < 4; ++rg) {
            int rl = i * 16 + quad * 4 + rg;
            float S1 = red1[rl * 5 + 0] + red1[rl * 5 + 1] + red1[rl * 5 + 2] + red1[rl * 5 + 3];
            float S2 = red2[rl * 5 + 0] + red2[rl * 5 + 1] + red2[rl * 5 + 2] + red2[rl * 5 + 3];
            float mean = S1 * (1.f / 256);
            float rstd = rsqrtf(S2 * (1.f / 256) - mean * mean + 1e-5f);
            int row = row0 + rl;
            if (row < M) {
                #pragma unroll
                for (int j = 0; j < 4; ++j) {
                    int col = wn + j * 16 + lrow;
                    float out = (acc[i][j][rg] - mean) * rstd * gj[j] + bj[j];
                    size_t o = (size_t)row * 256 + col;
                    x[o]  = out;
                    xb[o] = f2bf(out);
                }
            }
        }
}

// ---------------------------------------------------------------------------
// FUSED FFN: x = LN2(x + relu(xb@W1+b1)@W2 + b2); also xb, qb outputs.
// 32-row block; hidden in 4 chunks of 256, kept in LDS. Swizzled LDS tiles.
// ---------------------------------------------------------------------------
__global__ __launch_bounds__(256)
void ffn_kernel(const ushort_t* __restrict__ Axb, const ushort_t* __restrict__ W1t,
                const ushort_t* __restrict__ W2t,
                const float* __restrict__ bias1, const float* __restrict__ bias2,
                float* __restrict__ x, ushort_t* __restrict__ xb,
                ushort_t* __restrict__ qb, const ushort_t* __restrict__ posb,
                const float* __restrict__ lng, const float* __restrict__ lnb,
                int M)
{
    __shared__ short As[32 * 32];
    __shared__ short Bs[256 * 32];
    __shared__ short Hs[32 * 264];
    __shared__ float red1[32 * 5];
    __shared__ float red2[32 * 5];
    const int K = 256;
    int t    = threadIdx.x;
    int row0 = blockIdx.x * 32;
    int lane = t & 63;
    int w    = t >> 6;
    int wn   = w * 64;
    const int quad = lane >> 4, lrow = lane & 15;
    int srow = lane >> 2;
    const int sw = (((lane & 3) ^ ((lane >> 3) & 3)) * 8);
    const int rs = ((quad ^ ((lrow >> 1) & 3)) * 8);

    f32x4 acc[2][4];
    #pragma unroll
    for (int i = 0; i < 2; ++i)
        #pragma unroll
        for (int j = 0; j < 4; ++j)
            acc[i][j] = (f32x4){0.f, 0.f, 0.f, 0.f};

    const ushort_t* Ag = Axb + (size_t)(row0 + w * 16 + srow) * K + sw;  // w<2
    ushort_t* Al = (ushort_t*)&As[(w * 16) * 32];

    for (int c = 0; c < 4; ++c) {
        f32x4 hh[2][4];
        #pragma unroll
        for (int i = 0; i < 2; ++i)
            #pragma unroll
            for (int j = 0; j < 4; ++j)
                hh[i][j] = (f32x4){0.f, 0.f, 0.f, 0.f};

        // GEMM1: hh = xb[32xK] @ W1t[c*256+: 256 rows][K]^T
        const ushort_t* B1g = W1t + (size_t)(c * 256 + w * 64 + srow) * K + sw;
        for (int k0 = 0; k0 < K; k0 += 32) {
            if (w < 2) gload16(Ag + k0, Al);
            #pragma unroll
            for (int q = 0; q < 4; ++q)
                gload16(B1g + (size_t)(q * 16) * K + k0,
                        (ushort_t*)&Bs[(w * 64 + q * 16) * 32]);
            __syncthreads();
            bf16x8 af[2], bfr[4];
            #pragma unroll
            for (int i = 0; i < 2; ++i)
                af[i] = *(const bf16x8*)&As[(i * 16 + lrow) * 32 + rs];
            #pragma unroll
            for (int j = 0; j < 4; ++j)
                bfr[j] = *(const bf16x8*)&Bs[(wn + j * 16 + lrow) * 32 + rs];
            #pragma unroll
            for (int i = 0; i < 2; ++i)
                #pragma unroll
                for (int j = 0; j < 4; ++j)
                    hh[i][j] = __builtin_amdgcn_mfma_f32_16x16x32_bf16(af[i], bfr[j], hh[i][j], 0, 0, 0);
            __syncthreads();
        }
        // hidden chunk -> LDS (bias + relu, bf16)
        #pragma unroll
        for (int j = 0; j < 4; ++j) {
            int col = wn + j * 16 + lrow;
            float b1v = bias1[c * 256 + col];
            #pragma unroll
            for (int i = 0; i < 2; ++i)
                #pragma unroll
                for (int rg = 0; rg < 4; ++rg) {
                    int rl = i * 16 + quad * 4 + rg;
                    Hs[rl * 264 + col] = f2bf(fmaxf(hh[i][j][rg] + b1v, 0.f));
                }
        }
        __syncthreads();
        // GEMM2: acc += Hs[32x256] @ W2t[:, c*256+..]^T  (W2t: [256][1024])
        const ushort_t* B2g = W2t + (size_t)(w * 64 + srow) * 1024 + c * 256 + sw;
        for (int k0 = 0; k0 < 256; k0 += 32) {
            #pragma unroll
            for (int q = 0; q < 4; ++q)
                gload16(B2g + (size_t)(q * 16) * 1024 + k0,
                        (ushort_t*)&Bs[(w * 64 + q * 16) * 32]);
            __syncthreads();
            bf16x8 af[2], bfr[4];
            #pragma unroll
            for (int i = 0; i < 2; ++i)
                af[i] = *(const bf16x8*)&Hs[(i * 16 + lrow) * 264 + k0 + quad * 8];
            #pragma unroll
            for (int j = 0; j < 4; ++j)
                bfr[j] = *(const bf16x8*)&Bs[(wn + j * 16 + lrow) * 32 + rs];
            #pragma unroll
            for (int i = 0; i < 2; ++i)
                #pragma unroll
                for (int j = 0; j < 4; ++j)
                    acc[i][j] = __builtin_amdgcn_mfma_f32_16x16x32_bf16(af[i], bfr[j], acc[i][j], 0, 0, 0);
            __syncthreads();
        }
    }

    // ---- fused epilogue: v = x + (y + bias2); LN2; write x, xb, qb ----
    float gj[4], bj[4], bi[4];
    #pragma unroll
    for (int j = 0; j < 4; ++j) {
        int col = wn + j * 16 + lrow;
        gj[j] = lng[col];
        bj[j] = lnb[col];
        bi[j] = bias2[col];
    }

    #pragma unroll
    for (int i = 0; i < 2; ++i)
        #pragma unroll
        for (int rg = 0; rg < 4; ++rg) {
            int row = row0 + i * 16 + quad * 4 + rg;
            #pragma unroll
            for (int j = 0; j < 4; ++j) {
                int col = wn + j * 16 + lrow;
                float xres = (row < M) ? x[(size_t)row * 256 + col] : 0.f;
                acc[i][j][rg] += bi[j] + xres;
            }
            float p1 = acc[i][0][rg] + acc[i][1][rg] + acc[i][2][rg] + acc[i][3][rg];
            float p2 = acc[i][0][rg] * acc[i][0][rg] + acc[i][1][rg] * acc[i][1][rg]
                     + acc[i][2][rg] * acc[i][2][rg] + acc[i][3][rg] * acc[i][3][rg];
            p1 += __shfl_xor(p1, 1); p2 += __shfl_xor(p2, 1);
            p1 += __shfl_xor(p1, 2); p2 += __shfl_xor(p2, 2);
            p1 += __shfl_xor(p1, 4); p2 += __shfl_xor(p2, 4);
            p1 += __shfl_xor(p1, 8); p2 += __shfl_xor(p2, 8);
            if (lrow == 0) {
                int rl = i * 16 + quad * 4 + rg;
                red1[rl * 5 + w] = p1;
                red2[rl * 5 + w] = p2;
            }
        }
    __syncthreads();

    #pragma unroll
    for (int i = 0; i < 2; ++i)
        #pragma unroll
        for (int rg = 0; rg < 4; ++rg) {
            int rl = i * 16 + quad * 4 + rg;
            float S1 = red1[rl * 5 + 0] + red1[rl * 5 + 1] + red1[rl * 5 + 2] + red1[rl * 5 + 3];
            float S2 = red2[rl * 5 + 0] + red2[rl * 5 + 1] + red2[rl * 5 + 2] + red2[rl * 5 + 3];
            float mean = S1 * (1.f / 256);
            float rstd = rsqrtf(S2 * (1.f / 256) - mean * mean + 1e-5f);
            int row = row0 + rl;
            if (row < M) {
                #pragma unroll
                for (int j = 0; j < 4; ++j) {
                    int col = wn + j * 16 + lrow;
                    float out = (acc[i][j][rg] - mean) * rstd * gj[j] + bj[j];
                    size_t o = (size_t)row * 256 + col;
                    x[o]  = out;
                    xb[o] = f2bf(out);
                    qb[o] = f2bf(out + bf2f(posb[o]));
                }
            }
        }
}

// ---------------------------------------------------------------------------
// Fused deformable sampling, v7: XCD-pinned heads + 16B-lane gathers +
// relaxed VGPR cap for deep load pipelining.
// ---------------------------------------------------------------------------
__global__ __launch_bounds__(256, 4)
void sample_kernel(const ushort_t* __restrict__ valueb,
                   const ushort_t* __restrict__ offh,   // [NH][M][48]
                   const ushort_t* __restrict__ attnh,  // [NH][M][16]
                   ushort_t* __restrict__ sampb)
{
    __shared__ float wrec[16 * 168];
    __shared__ int   idxA[16 * 40];

    const int LD_[4]  = {4, 2, 1, 1};
    const int LH_[4]  = {48, 24, 12, 6};
    const int LW_[4]  = {48, 24, 12, 6};
    const int LS0_[4] = {0, 9216, 10368, 10512};

    int t   = threadIdx.x;
    int gl  = t >> 4;                   // local group 0..15
    int sub = t & 15;
    int h   = blockIdx.x;
    int r   = blockIdx.y * 16 + gl;
    bool valid = (r < M_ROWS);
    if (!valid) r = M_ROWS - 1;
    int b   = (r >= S_TOT) ? 1 : 0;
    int s   = r - b * S_TOT;

    float rx, ry, rz;
    {
        int j;
        if (s < 9216)       { j = s;         int qx = j % 48; int q2 = j / 48; int qy = q2 % 48; int qz = q2 / 48;
                              rx = (qx + 0.5f) * (1.f/48); ry = (qy + 0.5f) * (1.f/48); rz = (qz + 0.5f) * (1.f/4); }
        else if (s < 10368) { j = s - 9216;  int qx = j % 24; int q2 = j / 24; int qy = q2 % 24; int qz = q2 / 24;
                              rx = (qx + 0.5f) * (1.f/24); ry = (qy + 0.5f) * (1.f/24); rz = (qz + 0.5f) * (1.f/2); }
        else if (s < 10512) { j = s - 10368; int qx = j % 12; int qy = j / 12;
                              rx = (qx + 0.5f) * (1.f/12); ry = (qy + 0.5f) * (1.f/12); rz = 0.5f; }
        else                { j = s - 10512; int qx = j % 6;  int qy = j / 6;
                              rx = (qx + 0.5f) * (1.f/6);  ry = (qy + 0.5f) * (1.f/6);  rz = 0.5f; }
    }

    // ---- phase 1: one point per lane ----
    {
        int p = sub;
        float lg = bf2f(attnh[((size_t)h * M_ROWS + r) * 16 + p]);
        float mx = lg;
        mx = fmaxf(mx, __shfl_xor(mx, 1));
        mx = fmaxf(mx, __shfl_xor(mx, 2));
        mx = fmaxf(mx, __shfl_xor(mx, 4));
        mx = fmaxf(mx, __shfl_xor(mx, 8));
        float e = __expf(lg - mx);
        float sm = e;
        sm += __shfl_xor(sm, 1);
        sm += __shfl_xor(sm, 2);
        sm += __shfl_xor(sm, 4);
        sm += __shfl_xor(sm, 8);
        float aw = e / sm;

        int lvl = p >> 2;
        const int Dl = LD_[lvl], Hl = LH_[lvl], Wl = LW_[lvl];
        size_t base3 = ((size_t)h * M_ROWS + r) * 48 + p * 3;
        float cx = rx * Wl + bf2f(offh[base3 + 0]) - 0.5f;
        float cy = ry * Hl + bf2f(offh[base3 + 1]) - 0.5f;
        float cz = rz * Dl + bf2f(offh[base3 + 2]) - 0.5f;
        float xf = floorf(cx), yf = floorf(cy), zf = floorf(cz);
        float fx = cx - xf, fy = cy - yf, fz = cz - zf;
        int x0 = (int)xf, y0 = (int)yf, z0 = (int)zf;
        float wx0 = ((unsigned)x0       < (unsigned)Wl) ? 1.f - fx : 0.f;
        float wx1 = ((unsigned)(x0 + 1) < (unsigned)Wl) ? fx       : 0.f;
        float wy0 = ((unsigned)y0       < (unsigned)Hl) ? 1.f - fy : 0.f;
        float wy1 = ((unsigned)(y0 + 1) < (unsigned)Hl) ? fy       : 0.f;
        float wz0 = ((unsigned)z0       < (unsigned)Dl) ? (1.f - fz) * aw : 0.f;
        float wz1 = ((unsigned)(z0 + 1) < (unsigned)Dl) ? fz * aw       : 0.f;
        int xc = min(max(x0, -1), Wl - 1);
        int yc = min(max(y0, -1), Hl - 1);
        int zc = min(max(z0, -1), Dl - 1);
        int idx = LS0_[lvl] + (zc * Hl + yc) * Wl + xc;

        float* wp = &wrec[gl * 168 + p * 8];
        *(f32x4*)wp       = (f32x4){wz0 * wy0 * wx0, wz0 * wy0 * wx1,
                                    wz0 * wy1 * wx0, wz0 * wy1 * wx1};
        *(f32x4*)(wp + 4) = (f32x4){wz1 * wy0 * wx0, wz1 * wy0 * wx1,
                                    wz1 * wy1 * wx0, wz1 * wy1 * wx1};
        idxA[gl * 40 + p] = idx;
    }
    __syncthreads();

    // ---- phase 2: corner cr = (dy,dx), channel octet q ----
    int q  = sub & 3;
    int cr = sub >> 2;
    int dy = cr >> 1, dx = cr & 1;
    const ushort_t* vb = valueb + ((size_t)(b * NH_DIM + h) * S_TOT) * HD_DIM + q * 8;
    f32x4 accA = (f32x4){0.f, 0.f, 0.f, 0.f};
    f32x4 accB = (f32x4){0.f, 0.f, 0.f, 0.f};

    #pragma unroll
    for (int p = 0; p < 16; ++p) {
        const int lvl = p >> 2;
        const int Wl = LW_[lvl];
        const int HW = LH_[lvl] * LW_[lvl];
        float w0 = wrec[gl * 168 + p * 8 + cr];
        float w1 = wrec[gl * 168 + p * 8 + 4 + cr];
        int idx = idxA[gl * 40 + p] + dy * Wl + dx;
        const ushort_t* cb = vb + (long long)idx * HD_DIM;
        uint4 u0 = *(const uint4*)cb;
        uint4 u1 = *(const uint4*)(cb + HW * HD_DIM);
        accA += w0 * up2(u0.x, u0.y);
        accB += w0 * up2(u0.z, u0.w);
        accA += w1 * up2(u1.x, u1.y);
        accB += w1 * up2(u1.z, u1.w);
    }

    accA.x += __shfl_xor(accA.x, 4); accA.y += __shfl_xor(accA.y, 4);
    accA.z += __shfl_xor(accA.z, 4); accA.w += __shfl_xor(accA.w, 4);
    accB.x += __shfl_xor(accB.x, 4); accB.y += __shfl_xor(accB.y, 4);
    accB.z += __shfl_xor(accB.z, 4); accB.w += __shfl_xor(accB.w, 4);
    accA.x += __shfl_xor(accA.x, 8); accA.y += __shfl_xor(accA.y, 8);
    accA.z += __shfl_xor(accA.z, 8); accA.w += __shfl_xor(accA.w, 8);
    accB.x += __shfl_xor(accB.x, 8); accB.y += __shfl_xor(accB.y, 8);
    accB.z += __shfl_xor(accB.z, 8); accB.w += __shfl_xor(accB.w, 8);

    if (cr == 0 && valid) {
        ushort4 o1, o2;
        o1.x = f2bf(accA.x); o1.y = f2bf(accA.y); o1.z = f2bf(accA.z); o1.w = f2bf(accA.w);
        o2.x = f2bf(accB.x); o2.y = f2bf(accB.y); o2.z = f2bf(accB.z); o2.w = f2bf(accB.w);
        ushort_t* op = sampb + (size_t)r * E_DIM + h * HD_DIM + q * 8;
        *(ushort4*)op       = o1;
        *(ushort4*)(op + 4) = o2;
    }
}

// ---------------------------------------------------------------------------
extern "C" void kernel_launch(void* const* d_in, const int* in_sizes, int n_in,
                              void* d_out, int out_size, void* d_ws, size_t ws_size,
                              hipStream_t stream)
{
    const float* f0     = (const float*)d_in[0];
    const float* p0     = (const float*)d_in[1];
    const float* f1     = (const float*)d_in[2];
    const float* p1     = (const float*)d_in[3];
    const float* f2     = (const float*)d_in[4];
    const float* p2     = (const float*)d_in[5];
    const float* f3     = (const float*)d_in[6];
    const float* p3     = (const float*)d_in[7];
    const float* lemb   = (const float*)d_in[8];
    const float* W_off  = (const float*)d_in[9];
    const float* b_off  = (const float*)d_in[10];
    const float* W_attn = (const float*)d_in[11];
    const float* b_attn = (const float*)d_in[12];
    const float* W_val  = (const float*)d_in[13];
    const float* b_val  = (const float*)d_in[14];
    const float* W_out  = (const float*)d_in[15];
    const float* b_out  = (const float*)d_in[16];
    const float* ln1_g  = (const float*)d_in[17];
    const float* ln1_b  = (const float*)d_in[18];
    const float* W_ff1  = (const float*)d_in[19];
    const float* b_ff1  = (const float*)d_in[20];
    const float* W_ff2  = (const float*)d_in[21];
    const float* b_ff2  = (const float*)d_in[22];
    const float* ln2_g  = (const float*)d_in[23];
    const float* ln2_b  = (const float*)d_in[24];

    float* x = (float*)d_out;
    char*  w = (char*)d_ws;

    // ws layout (bytes)
    ushort_t* posb   = (ushort_t*)(w + 0);                   // 10,813,440
    // value region: 256KB front guard | (B,NH,S,HD) bf16 | 128KB back guard
    ushort_t* valueb = (ushort_t*)(w + 21626880 + 262144);
    char*     region =            (w + 34525184);            // 43,253,760
    ushort_t* offh   = (ushort_t*)(region);                  // [NH][M][48] 16,220,160
    ushort_t* attnh  = (ushort_t*)(region + 16220160);       // [NH][M][16]  5,406,720
    ushort_t* sampb  = (ushort_t*)(region + 21626880);       // 10,813,440
    ushort_t* xb     = (ushort_t*)(w + 77778944);            // 10,813,440
    ushort_t* qb     = (ushort_t*)(w + 88592384);            // 10,813,440
    ushort_t* wb     = (ushort_t*)(w + 99405824);            //  9,437,184

    // Combined attention weight: per layer 768 rows x 256 K
    ushort_t* Wc_t = wb;              // [6][768][256]
    ushort_t* Wp_t = wb + 1179648;    // [6][256][256]
    ushort_t* W1_t = wb + 1572864;    // [6][1024][256]
    ushort_t* W2_t = wb + 3145728;    // [6][256][1024]

    dim3 blk(256);

    transpose_cvt_kernel<<<dim3(8, 8, 6),  blk, 0, stream>>>(W_val,  Wc_t, 256, 256,  196608, 0);
    transpose_cvt_kernel<<<dim3(12, 8, 6), blk, 0, stream>>>(W_off,  Wc_t, 256, 384,  196608, 256);
    transpose_cvt_kernel<<<dim3(4, 8, 6),  blk, 0, stream>>>(W_attn, Wc_t, 256, 128,  196608, 640);
    transpose_cvt_kernel<<<dim3(8, 8, 6),  blk, 0, stream>>>(W_out,  Wp_t, 256, 256,   65536, 0);
    transpose_cvt_kernel<<<dim3(32, 8, 6), blk, 0, stream>>>(W_ff1,  W1_t, 256, 1024, 262144, 0);
    transpose_cvt_kernel<<<dim3(8, 32, 6), blk, 0, stream>>>(W_ff2,  W2_t, 1024, 256, 262144, 0);

    assemble_kernel<<<(M_ROWS * E_DIM) / 256, blk, 0, stream>>>(
        f0, p0, f1, p1, f2, p2, f3, p3, lemb, x, posb, xb, qb);

    const int MT = M_PAD / 64;               // 330
    const int LT = M_PAD / 32;               // 660
    const int SB = (M_ROWS + 15) / 16;       // 1319
    for (int l = 0; l < NLAYERS; ++l) {
        gemm_part1<<<dim3(3, MT), blk, 0, stream>>>(
            xb, qb, Wc_t + l * 196608,
            b_val + l * 256, b_off + l * 384, b_attn + l * 128,
            valueb, offh, attnh, M_ROWS);
        sample_kernel<<<dim3(NH_DIM, SB), blk, 0, stream>>>(valueb, offh, attnh, sampb);
        gemm_ln<<<LT, blk, 0, stream>>>(
            sampb, Wp_t + l * 65536, b_out + l * 256,
            x, xb, ln1_g + l * 256, ln1_b + l * 256, M_ROWS);
        ffn_kernel<<<LT, blk, 0, stream>>>(
            xb, W1_t + l * 262144, W2_t + l * 262144,
            b_ff1 + l * 1024, b_ff2 + l * 256,
            x, xb, qb, posb,
            ln2_g + l * 256, ln2_b + l * 256, M_ROWS);
    }
}